// Round 20
// baseline (196.509 us; speedup 1.0000x reference)
//
#include <hip/hip_runtime.h>

#define NN 50000
#define NE 800000
#define KC 512
#define OC 256  // 128 mu cols | 128 logstd cols
#define NB_SCAN 196   // ceil(NN/256)
#define NCB 3125      // ceil(NE/256) count/scatter blocks

typedef float f32x4 __attribute__((ext_vector_type(4)));
typedef short bf16x8 __attribute__((ext_vector_type(8)));

__device__ __forceinline__ unsigned f2bf(float f) {
    union { float f; unsigned u; } v; v.f = f;
    return (v.u + 0x7FFFu + ((v.u >> 16) & 1u)) >> 16;  // RNE
}
__device__ __forceinline__ float bf2f(unsigned short b) {
    union { unsigned u; float f; } v; v.u = ((unsigned)b) << 16;
    return v.f;
}

// ---------------- fused: degree count (blocks 0..NCB-1) + W convert (blocks NCB..) ----------------
__global__ __launch_bounds__(256) void prep0_kernel(const int* __restrict__ ei,
                                                    int* __restrict__ deg,
                                                    const float* __restrict__ Wmu,
                                                    const float* __restrict__ Wls,
                                                    uint4* __restrict__ Wc) {
    int bid = blockIdx.x;
    int tid = threadIdx.x;
    if (bid < NCB) {
        int e = bid * 256 + tid;
        if (e < NE) atomicAdd(&deg[ei[NE + e]], 1);
    } else {
        int idx = (bid - NCB) * 256 + tid;  // 16384 slots
        int kb = idx >> 10;
        int rem = idx & 1023;
        int wf = rem >> 6;
        int lane = rem & 63;
        int g4 = lane >> 4;
        int i16 = lane & 15;
        int col = (wf >> 2) * 64 + (wf & 3) * 16 + i16;
        int k0 = kb * 32 + g4 * 8;
        const float* Wsrc = (col < 128) ? (Wmu + col) : (Wls + (col - 128));
        unsigned o[4];
#pragma unroll
        for (int p = 0; p < 4; ++p) {
            float lo = Wsrc[(size_t)(k0 + 2 * p) * 128];
            float hi = Wsrc[(size_t)(k0 + 2 * p + 1) * 128];
            o[p] = f2bf(lo) | (f2bf(hi) << 16);
        }
        uint4 v;
        v.x = o[0]; v.y = o[1]; v.z = o[2]; v.w = o[3];
        Wc[idx] = v;
    }
}

// ---------------- scan A: per-block sums ----------------
__global__ __launch_bounds__(256) void scan_part_kernel(const int* __restrict__ deg,
                                                        int* __restrict__ partial) {
    int tid = threadIdx.x;
    int i = blockIdx.x * 256 + tid;
    int v = (i < NN) ? deg[i] : 0;
#pragma unroll
    for (int off = 32; off > 0; off >>= 1) v += __shfl_down(v, off, 64);
    __shared__ int wsum[4];
    if ((tid & 63) == 0) wsum[tid >> 6] = v;
    __syncthreads();
    if (tid == 0) partial[blockIdx.x] = wsum[0] + wsum[1] + wsum[2] + wsum[3];
}

// ---------------- scan B (fused): inline scan of 196 partials + per-block apply ----------------
__global__ __launch_bounds__(256) void scan_apply_kernel(const int* __restrict__ deg,
                                                         const int* __restrict__ partial,
                                                         int* __restrict__ row_start,
                                                         int* __restrict__ cursor,
                                                         float* __restrict__ dinv) {
    __shared__ int plds[256];
    __shared__ int wsum[4];
    int tid = threadIdx.x;
    int lane = tid & 63;
    int w = tid >> 6;

    int pv = (tid < NB_SCAN) ? partial[tid] : 0;
    plds[tid] = pv;
    __syncthreads();
    for (int off = 1; off < 256; off <<= 1) {
        int t = (tid >= off) ? plds[tid - off] : 0;
        __syncthreads();
        plds[tid] += t;
        __syncthreads();
    }
    int boff = (blockIdx.x == 0) ? 0 : plds[blockIdx.x - 1];

    int i = blockIdx.x * 256 + tid;
    int d = (i < NN) ? deg[i] : 0;
    int v = d;
#pragma unroll
    for (int off = 1; off < 64; off <<= 1) {
        int t = __shfl_up(v, off, 64);
        if (lane >= off) v += t;
    }
    if (lane == 63) wsum[w] = v;
    __syncthreads();
    int wof = 0;
    for (int k = 0; k < w; ++k) wof += wsum[k];
    int excl = boff + wof + v - d;
    if (i < NN) {
        row_start[i] = excl;
        cursor[i] = excl;
        dinv[i] = rsqrtf((float)(d + 1));  // +1 self-loop
    }
    if (i == NN - 1) row_start[NN] = excl + d;
}

// ---------------- scatter edges into CSR (by dst) ----------------
__global__ __launch_bounds__(256) void scatter_kernel(const int* __restrict__ ei,
                                                      int* __restrict__ cursor,
                                                      int* __restrict__ csr_src) {
    int e = blockIdx.x * 256 + threadIdx.x;
    if (e < NE) {
        int d = ei[NE + e];
        int pos = atomicAdd(&cursor[d], 1);
        __builtin_nontemporal_store(ei[e], &csr_src[pos]);
    }
}

// ---------------- MFMA GEMM (R12-proven): hs[N][256] = bf16(x @ [Wmu|Wls]) * dinv ----------------
// BM=32, 4 waves; A via global_load_lds DMA into f32 LDS, source pre-swizzled
// (c'=c^(r&15), m'=m^((r>>2&1)*4)); cvt_pk at frag read; B 3-buf reg prefetch.
__global__ __launch_bounds__(256, 4) void gemm_kernel(const float* __restrict__ x,
                                                      const uint4* __restrict__ Wc,
                                                      const float* __restrict__ dinv,
                                                      unsigned short* __restrict__ hs) {
    __shared__ __align__(16) float Af[2][32 * 128];  // 2 x 16 KB

    int tid = threadIdx.x;
    int lane = tid & 63;
    int w = tid >> 6;
    int r0 = blockIdx.x * 32;
    int i16 = lane & 15;
    int g4 = lane >> 4;

    const float* srcp[4];
#pragma unroll
    for (int j = 0; j < 4; ++j) {
        int r = w * 8 + j * 2 + (lane >> 5);
        int gr = r0 + r;
        if (gr > NN - 1) gr = NN - 1;
        int cp = (lane & 31) >> 1;
        int mp = (lane & 1) * 4;
        int c = cp ^ (r & 15);
        int m = mp ^ (((r >> 2) & 1) * 4);
        srcp[j] = x + (size_t)gr * KC + c * 8 + m;
    }
    auto dmaA = [&](int buf, int S) {
#pragma unroll
        for (int j = 0; j < 4; ++j) {
            __builtin_amdgcn_global_load_lds(
                (const __attribute__((address_space(1))) void*)(srcp[j] + S * 128),
                (__attribute__((address_space(3))) void*)&Af[buf][(w * 4 + j) * 256], 16, 0, 0);
        }
    };

    auto readA = [&](int buf, int ks, int fr) -> bf16x8 {
        int r = fr * 16 + i16;
        int c = ks * 4 + g4;
        int cc = c ^ (r & 15);
        int mo = ((r >> 2) & 1) * 4;
        const float* p = &Af[buf][r * 128 + cc * 8];
        f32x4 lo = *(const f32x4*)(p + mo);
        f32x4 hi = *(const f32x4*)(p + (mo ^ 4));
        unsigned o0, o1, o2, o3;
        asm("v_cvt_pk_bf16_f32 %0, %1, %2" : "=v"(o0) : "v"(lo.x), "v"(lo.y));
        asm("v_cvt_pk_bf16_f32 %0, %1, %2" : "=v"(o1) : "v"(lo.z), "v"(lo.w));
        asm("v_cvt_pk_bf16_f32 %0, %1, %2" : "=v"(o2) : "v"(hi.x), "v"(hi.y));
        asm("v_cvt_pk_bf16_f32 %0, %1, %2" : "=v"(o3) : "v"(hi.z), "v"(hi.w));
        union { unsigned u[4]; bf16x8 v; } res;
        res.u[0] = o0; res.u[1] = o1; res.u[2] = o2; res.u[3] = o3;
        return res.v;
    };

    const uint4* wbase = Wc + (size_t)(w * 4) * 64 + lane;
    uint4 bb[3][4];
    auto loadB = [&](int dbuf, int kb) {
#pragma unroll
        for (int fc = 0; fc < 4; ++fc) bb[dbuf][fc] = wbase[kb * 1024 + fc * 64];
    };

    f32x4 acc[2][4];
    f32x4 zz = {0.f, 0.f, 0.f, 0.f};
#pragma unroll
    for (int a = 0; a < 2; ++a)
#pragma unroll
        for (int b = 0; b < 4; ++b) acc[a][b] = zz;

    dmaA(0, 0);
    loadB(0, 0);
    loadB(1, 1);
    __syncthreads();  // drains DMA S0

#pragma unroll
    for (int S = 0; S < 4; ++S) {
        if (S < 3) dmaA((S + 1) & 1, S + 1);
#pragma unroll
        for (int ks = 0; ks < 4; ++ks) {
            const int kb = S * 4 + ks;
            if (kb + 2 < 16) loadB((kb + 2) % 3, kb + 2);
            bf16x8 af0 = readA(S & 1, ks, 0);
            bf16x8 af1 = readA(S & 1, ks, 1);
            const int cur = kb % 3;
#pragma unroll
            for (int fc = 0; fc < 4; ++fc) {
                bf16x8 bfrag = *(const bf16x8*)&bb[cur][fc];
                acc[0][fc] = __builtin_amdgcn_mfma_f32_16x16x32_bf16(af0, bfrag, acc[0][fc], 0, 0, 0);
                acc[1][fc] = __builtin_amdgcn_mfma_f32_16x16x32_bf16(af1, bfrag, acc[1][fc], 0, 0, 0);
            }
        }
        if (S < 3) __syncthreads();
    }

#pragma unroll
    for (int fr = 0; fr < 2; ++fr) {
#pragma unroll
        for (int r = 0; r < 4; ++r) {
            int gr = r0 + fr * 16 + g4 * 4 + r;
            if (gr < NN) {
                float dv = dinv[gr];
#pragma unroll
                for (int fc = 0; fc < 4; ++fc) {
                    int col = w * 64 + fc * 16 + i16;
                    hs[(size_t)gr * OC + col] = (unsigned short)f2bf(acc[fr][fc][r] * dv);
                }
            }
        }
    }
}

// ---------------- aggregation: out = dinv[n]*(sum_e hs[src] + hs[n]) + b ----------------
__global__ __launch_bounds__(256) void aggregate_kernel(const unsigned short* __restrict__ hs,
                                                        const int* __restrict__ row_start,
                                                        const int* __restrict__ csr_src,
                                                        const float* __restrict__ dinv,
                                                        const float* __restrict__ bmu,
                                                        const float* __restrict__ bls,
                                                        float* __restrict__ out) {
    int tid = threadIdx.x;
    int lane = tid & 63;
    int node = blockIdx.x * 4 + (tid >> 6);

    const unsigned short* hrow = hs + lane * 4;  // lane covers cols 4l..4l+3
    float acc0, acc1, acc2, acc3;
    {
        ushort4 v = *(const ushort4*)&hrow[(size_t)node * OC];
        acc0 = bf2f(v.x);
        acc1 = bf2f(v.y);
        acc2 = bf2f(v.z);
        acc3 = bf2f(v.w);
    }
    int rs = row_start[node], re = row_start[node + 1];
    int e = rs;
    for (; e + 8 <= re; e += 8) {
        int s[8];
#pragma unroll
        for (int q = 0; q < 8; ++q) s[q] = csr_src[e + q];
        ushort4 v[8];
#pragma unroll
        for (int q = 0; q < 8; ++q) v[q] = *(const ushort4*)&hrow[(size_t)s[q] * OC];
#pragma unroll
        for (int q = 0; q < 8; ++q) {
            acc0 += bf2f(v[q].x);
            acc1 += bf2f(v[q].y);
            acc2 += bf2f(v[q].z);
            acc3 += bf2f(v[q].w);
        }
    }
    if (e + 4 <= re) {
        int s[4];
#pragma unroll
        for (int q = 0; q < 4; ++q) s[q] = csr_src[e + q];
        ushort4 v[4];
#pragma unroll
        for (int q = 0; q < 4; ++q) v[q] = *(const ushort4*)&hrow[(size_t)s[q] * OC];
#pragma unroll
        for (int q = 0; q < 4; ++q) {
            acc0 += bf2f(v[q].x);
            acc1 += bf2f(v[q].y);
            acc2 += bf2f(v[q].z);
            acc3 += bf2f(v[q].w);
        }
        e += 4;
    }
    for (; e < re; ++e) {
        int s0 = csr_src[e];
        ushort4 v0 = *(const ushort4*)&hrow[(size_t)s0 * OC];
        acc0 += bf2f(v0.x);
        acc1 += bf2f(v0.y);
        acc2 += bf2f(v0.z);
        acc3 += bf2f(v0.w);
    }
    float dn = dinv[node];
    if (lane < 32) {
        f32x4 b = *(const f32x4*)&bmu[lane * 4];
        f32x4 r;
        r.x = acc0 * dn + b.x;
        r.y = acc1 * dn + b.y;
        r.z = acc2 * dn + b.z;
        r.w = acc3 * dn + b.w;
        __builtin_nontemporal_store(r, (f32x4*)(out + (size_t)node * 128 + lane * 4));
    } else {
        f32x4 b = *(const f32x4*)&bls[(lane - 32) * 4];
        f32x4 r;
        r.x = acc0 * dn + b.x;
        r.y = acc1 * dn + b.y;
        r.z = acc2 * dn + b.z;
        r.w = acc3 * dn + b.w;
        __builtin_nontemporal_store(
            r, (f32x4*)(out + (size_t)NN * 128 + (size_t)node * 128 + (lane - 32) * 4));
    }
}

extern "C" void kernel_launch(void* const* d_in, const int* in_sizes, int n_in,
                              void* d_out, int out_size, void* d_ws, size_t ws_size,
                              hipStream_t stream) {
    const float* x = (const float*)d_in[0];
    const int* ei = (const int*)d_in[1];  // [2][NE]: src then dst
    const float* Wmu = (const float*)d_in[2];
    const float* bmu = (const float*)d_in[3];
    const float* Wls = (const float*)d_in[4];
    const float* bls = (const float*)d_in[5];
    float* out = (float*)d_out;

    char* ws = (char*)d_ws;
    size_t off = 0;
    auto alloc = [&](size_t bytes) {
        void* p = ws + off;
        off += (bytes + 255) & ~(size_t)255;
        return p;
    };
    unsigned short* hs = (unsigned short*)alloc((size_t)NN * OC * sizeof(unsigned short));  // 25.6 MB
    uint4* Wc = (uint4*)alloc((size_t)16384 * 16);                                          // 256 KB
    int* deg = (int*)alloc((size_t)NN * sizeof(int));
    int* row_start = (int*)alloc((size_t)(NN + 1) * sizeof(int));
    int* cursor = (int*)alloc((size_t)NN * sizeof(int));
    int* csr_src = (int*)alloc((size_t)NE * sizeof(int));
    float* dinv = (float*)alloc((size_t)NN * sizeof(float));
    int* partial = (int*)alloc((size_t)NB_SCAN * sizeof(int));

    hipMemsetAsync(deg, 0, (size_t)NN * sizeof(int), stream);

    prep0_kernel<<<NCB + 64, 256, 0, stream>>>(ei, deg, Wmu, Wls, Wc);
    scan_part_kernel<<<NB_SCAN, 256, 0, stream>>>(deg, partial);
    scan_apply_kernel<<<NB_SCAN, 256, 0, stream>>>(deg, partial, row_start, cursor, dinv);
    scatter_kernel<<<NCB, 256, 0, stream>>>(ei, cursor, csr_src);
    gemm_kernel<<<(NN + 31) / 32, 256, 0, stream>>>(x, Wc, dinv, hs);
    aggregate_kernel<<<NN / 4, 256, 0, stream>>>(hs, row_start, csr_src, dinv, bmu, bls, out);
}

// Round 22
// 186.085 us; speedup vs baseline: 1.0560x; 1.0560x over previous
//
#include <hip/hip_runtime.h>

#define NN 50000
#define NE 800000
#define KC 512
#define OC 256  // 128 mu cols | 128 logstd cols
#define NB_SCAN 196   // ceil(NN/256)
#define NCB 3125      // ceil(NE/256) count/scatter blocks
#define NGB 1563      // ceil(NN/32) gemm blocks

typedef float f32x4 __attribute__((ext_vector_type(4)));
typedef short bf16x8 __attribute__((ext_vector_type(8)));

__device__ __forceinline__ unsigned f2bf(float f) {
    union { float f; unsigned u; } v; v.f = f;
    return (v.u + 0x7FFFu + ((v.u >> 16) & 1u)) >> 16;  // RNE
}
__device__ __forceinline__ float bf2f(unsigned short b) {
    union { unsigned u; float f; } v; v.u = ((unsigned)b) << 16;
    return v.f;
}

// ---------------- fused: degree count (blocks 0..NCB-1) + W convert (blocks NCB..) ----------------
// convw layout: slot = kb*1024 + wf*64 + lane holds W[k=kb*32+g4*8..+7][col=(wf>>2)*64+(wf&3)*16+i16]
__global__ __launch_bounds__(256) void prep0_kernel(const int* __restrict__ ei,
                                                    int* __restrict__ deg,
                                                    const float* __restrict__ Wmu,
                                                    const float* __restrict__ Wls,
                                                    uint4* __restrict__ Wc) {
    int bid = blockIdx.x;
    int tid = threadIdx.x;
    if (bid < NCB) {
        int e = bid * 256 + tid;
        if (e < NE) atomicAdd(&deg[ei[NE + e]], 1);
    } else {
        int idx = (bid - NCB) * 256 + tid;  // 16384 slots
        int kb = idx >> 10;
        int rem = idx & 1023;
        int wf = rem >> 6;
        int lane = rem & 63;
        int g4 = lane >> 4;
        int i16 = lane & 15;
        int col = (wf >> 2) * 64 + (wf & 3) * 16 + i16;
        int k0 = kb * 32 + g4 * 8;
        const float* Wsrc = (col < 128) ? (Wmu + col) : (Wls + (col - 128));
        unsigned o[4];
#pragma unroll
        for (int p = 0; p < 4; ++p) {
            float lo = Wsrc[(size_t)(k0 + 2 * p) * 128];
            float hi = Wsrc[(size_t)(k0 + 2 * p + 1) * 128];
            o[p] = f2bf(lo) | (f2bf(hi) << 16);
        }
        uint4 v;
        v.x = o[0]; v.y = o[1]; v.z = o[2]; v.w = o[3];
        Wc[idx] = v;
    }
}

// ---------------- scan A: per-block sums ----------------
__global__ __launch_bounds__(256) void scan_part_kernel(const int* __restrict__ deg,
                                                        int* __restrict__ partial) {
    int tid = threadIdx.x;
    int i = blockIdx.x * 256 + tid;
    int v = (i < NN) ? deg[i] : 0;
#pragma unroll
    for (int off = 32; off > 0; off >>= 1) v += __shfl_down(v, off, 64);
    __shared__ int wsum[4];
    if ((tid & 63) == 0) wsum[tid >> 6] = v;
    __syncthreads();
    if (tid == 0) partial[blockIdx.x] = wsum[0] + wsum[1] + wsum[2] + wsum[3];
}

// ---------------- scan B (fused): inline scan of 196 partials + per-block apply ----------------
__global__ __launch_bounds__(256) void scan_apply_kernel(const int* __restrict__ deg,
                                                         const int* __restrict__ partial,
                                                         int* __restrict__ row_start,
                                                         int* __restrict__ cursor,
                                                         float* __restrict__ dinv) {
    __shared__ int plds[256];
    __shared__ int wsum[4];
    int tid = threadIdx.x;
    int lane = tid & 63;
    int w = tid >> 6;

    int pv = (tid < NB_SCAN) ? partial[tid] : 0;
    plds[tid] = pv;
    __syncthreads();
    for (int off = 1; off < 256; off <<= 1) {
        int t = (tid >= off) ? plds[tid - off] : 0;
        __syncthreads();
        plds[tid] += t;
        __syncthreads();
    }
    int boff = (blockIdx.x == 0) ? 0 : plds[blockIdx.x - 1];

    int i = blockIdx.x * 256 + tid;
    int d = (i < NN) ? deg[i] : 0;
    int v = d;
#pragma unroll
    for (int off = 1; off < 64; off <<= 1) {
        int t = __shfl_up(v, off, 64);
        if (lane >= off) v += t;
    }
    if (lane == 63) wsum[w] = v;
    __syncthreads();
    int wof = 0;
    for (int k = 0; k < w; ++k) wof += wsum[k];
    int excl = boff + wof + v - d;
    if (i < NN) {
        row_start[i] = excl;
        cursor[i] = excl;
        dinv[i] = rsqrtf((float)(d + 1));  // +1 self-loop
    }
    if (i == NN - 1) row_start[NN] = excl + d;
}

// ---------------- fused: MFMA GEMM (blocks 0..NGB-1) + edge scatter (blocks NGB..) ----------------
// GEMM (R12-proven): BM=32, 4 waves; A via global_load_lds DMA into f32 LDS, source
// pre-swizzled (c'=c^(r&15), m'=m^((r>>2&1)*4)); cvt_pk at frag read; B 3-buf reg prefetch.
// Scatter runs concurrently on its own blocks, hidden under the latency-bound gemm.
__global__ __launch_bounds__(256, 4) void gemm_scatter_kernel(const float* __restrict__ x,
                                                              const uint4* __restrict__ Wc,
                                                              const float* __restrict__ dinv,
                                                              unsigned short* __restrict__ hs,
                                                              const int* __restrict__ ei,
                                                              int* __restrict__ cursor,
                                                              int* __restrict__ csr_src) {
    __shared__ __align__(16) float Af[2][32 * 128];  // 2 x 16 KB (gemm blocks only)

    int bid = blockIdx.x;
    int tid = threadIdx.x;

    if (bid >= NGB) {  // ---- scatter part ----
        int e = (bid - NGB) * 256 + tid;
        if (e < NE) {
            int d = ei[NE + e];
            int pos = atomicAdd(&cursor[d], 1);
            csr_src[pos] = ei[e];
        }
        return;
    }

    // ---- gemm part (R12 verbatim) ----
    int lane = tid & 63;
    int w = tid >> 6;
    int r0 = bid * 32;
    int i16 = lane & 15;
    int g4 = lane >> 4;

    const float* srcp[4];
#pragma unroll
    for (int j = 0; j < 4; ++j) {
        int r = w * 8 + j * 2 + (lane >> 5);
        int gr = r0 + r;
        if (gr > NN - 1) gr = NN - 1;
        int cp = (lane & 31) >> 1;
        int mp = (lane & 1) * 4;
        int c = cp ^ (r & 15);
        int m = mp ^ (((r >> 2) & 1) * 4);
        srcp[j] = x + (size_t)gr * KC + c * 8 + m;
    }
    auto dmaA = [&](int buf, int S) {
#pragma unroll
        for (int j = 0; j < 4; ++j) {
            __builtin_amdgcn_global_load_lds(
                (const __attribute__((address_space(1))) void*)(srcp[j] + S * 128),
                (__attribute__((address_space(3))) void*)&Af[buf][(w * 4 + j) * 256], 16, 0, 0);
        }
    };

    auto readA = [&](int buf, int ks, int fr) -> bf16x8 {
        int r = fr * 16 + i16;
        int c = ks * 4 + g4;
        int cc = c ^ (r & 15);
        int mo = ((r >> 2) & 1) * 4;
        const float* p = &Af[buf][r * 128 + cc * 8];
        f32x4 lo = *(const f32x4*)(p + mo);
        f32x4 hi = *(const f32x4*)(p + (mo ^ 4));
        unsigned o0, o1, o2, o3;
        asm("v_cvt_pk_bf16_f32 %0, %1, %2" : "=v"(o0) : "v"(lo.x), "v"(lo.y));
        asm("v_cvt_pk_bf16_f32 %0, %1, %2" : "=v"(o1) : "v"(lo.z), "v"(lo.w));
        asm("v_cvt_pk_bf16_f32 %0, %1, %2" : "=v"(o2) : "v"(hi.x), "v"(hi.y));
        asm("v_cvt_pk_bf16_f32 %0, %1, %2" : "=v"(o3) : "v"(hi.z), "v"(hi.w));
        union { unsigned u[4]; bf16x8 v; } res;
        res.u[0] = o0; res.u[1] = o1; res.u[2] = o2; res.u[3] = o3;
        return res.v;
    };

    const uint4* wbase = Wc + (size_t)(w * 4) * 64 + lane;
    uint4 bb[3][4];
    auto loadB = [&](int dbuf, int kb) {
#pragma unroll
        for (int fc = 0; fc < 4; ++fc) bb[dbuf][fc] = wbase[kb * 1024 + fc * 64];
    };

    f32x4 acc[2][4];
    f32x4 zz = {0.f, 0.f, 0.f, 0.f};
#pragma unroll
    for (int a = 0; a < 2; ++a)
#pragma unroll
        for (int b = 0; b < 4; ++b) acc[a][b] = zz;

    dmaA(0, 0);
    loadB(0, 0);
    loadB(1, 1);
    __syncthreads();  // drains DMA S0

#pragma unroll
    for (int S = 0; S < 4; ++S) {
        if (S < 3) dmaA((S + 1) & 1, S + 1);
#pragma unroll
        for (int ks = 0; ks < 4; ++ks) {
            const int kb = S * 4 + ks;
            if (kb + 2 < 16) loadB((kb + 2) % 3, kb + 2);
            bf16x8 af0 = readA(S & 1, ks, 0);
            bf16x8 af1 = readA(S & 1, ks, 1);
            const int cur = kb % 3;
#pragma unroll
            for (int fc = 0; fc < 4; ++fc) {
                bf16x8 bfrag = *(const bf16x8*)&bb[cur][fc];
                acc[0][fc] = __builtin_amdgcn_mfma_f32_16x16x32_bf16(af0, bfrag, acc[0][fc], 0, 0, 0);
                acc[1][fc] = __builtin_amdgcn_mfma_f32_16x16x32_bf16(af1, bfrag, acc[1][fc], 0, 0, 0);
            }
        }
        if (S < 3) __syncthreads();
    }

#pragma unroll
    for (int fr = 0; fr < 2; ++fr) {
#pragma unroll
        for (int r = 0; r < 4; ++r) {
            int gr = r0 + fr * 16 + g4 * 4 + r;
            if (gr < NN) {
                float dv = dinv[gr];
#pragma unroll
                for (int fc = 0; fc < 4; ++fc) {
                    int col = w * 64 + fc * 16 + i16;
                    hs[(size_t)gr * OC + col] = (unsigned short)f2bf(acc[fr][fc][r] * dv);
                }
            }
        }
    }
}

// ---------------- aggregation: out = dinv[n]*(sum_e hs[src] + hs[n]) + b ----------------
__global__ __launch_bounds__(256) void aggregate_kernel(const unsigned short* __restrict__ hs,
                                                        const int* __restrict__ row_start,
                                                        const int* __restrict__ csr_src,
                                                        const float* __restrict__ dinv,
                                                        const float* __restrict__ bmu,
                                                        const float* __restrict__ bls,
                                                        float* __restrict__ out) {
    int tid = threadIdx.x;
    int lane = tid & 63;
    int node = blockIdx.x * 4 + (tid >> 6);

    const unsigned short* hrow = hs + lane * 4;  // lane covers cols 4l..4l+3
    float acc0, acc1, acc2, acc3;
    {
        ushort4 v = *(const ushort4*)&hrow[(size_t)node * OC];
        acc0 = bf2f(v.x);
        acc1 = bf2f(v.y);
        acc2 = bf2f(v.z);
        acc3 = bf2f(v.w);
    }
    int rs = row_start[node], re = row_start[node + 1];
    int e = rs;
    for (; e + 8 <= re; e += 8) {
        int s[8];
#pragma unroll
        for (int q = 0; q < 8; ++q) s[q] = csr_src[e + q];
        ushort4 v[8];
#pragma unroll
        for (int q = 0; q < 8; ++q) v[q] = *(const ushort4*)&hrow[(size_t)s[q] * OC];
#pragma unroll
        for (int q = 0; q < 8; ++q) {
            acc0 += bf2f(v[q].x);
            acc1 += bf2f(v[q].y);
            acc2 += bf2f(v[q].z);
            acc3 += bf2f(v[q].w);
        }
    }
    if (e + 4 <= re) {
        int s[4];
#pragma unroll
        for (int q = 0; q < 4; ++q) s[q] = csr_src[e + q];
        ushort4 v[4];
#pragma unroll
        for (int q = 0; q < 4; ++q) v[q] = *(const ushort4*)&hrow[(size_t)s[q] * OC];
#pragma unroll
        for (int q = 0; q < 4; ++q) {
            acc0 += bf2f(v[q].x);
            acc1 += bf2f(v[q].y);
            acc2 += bf2f(v[q].z);
            acc3 += bf2f(v[q].w);
        }
        e += 4;
    }
    for (; e < re; ++e) {
        int s0 = csr_src[e];
        ushort4 v0 = *(const ushort4*)&hrow[(size_t)s0 * OC];
        acc0 += bf2f(v0.x);
        acc1 += bf2f(v0.y);
        acc2 += bf2f(v0.z);
        acc3 += bf2f(v0.w);
    }
    float dn = dinv[node];
    if (lane < 32) {
        f32x4 b = *(const f32x4*)&bmu[lane * 4];
        f32x4 r;
        r.x = acc0 * dn + b.x;
        r.y = acc1 * dn + b.y;
        r.z = acc2 * dn + b.z;
        r.w = acc3 * dn + b.w;
        __builtin_nontemporal_store(r, (f32x4*)(out + (size_t)node * 128 + lane * 4));
    } else {
        f32x4 b = *(const f32x4*)&bls[(lane - 32) * 4];
        f32x4 r;
        r.x = acc0 * dn + b.x;
        r.y = acc1 * dn + b.y;
        r.z = acc2 * dn + b.z;
        r.w = acc3 * dn + b.w;
        __builtin_nontemporal_store(
            r, (f32x4*)(out + (size_t)NN * 128 + (size_t)node * 128 + (lane - 32) * 4));
    }
}

extern "C" void kernel_launch(void* const* d_in, const int* in_sizes, int n_in,
                              void* d_out, int out_size, void* d_ws, size_t ws_size,
                              hipStream_t stream) {
    const float* x = (const float*)d_in[0];
    const int* ei = (const int*)d_in[1];  // [2][NE]: src then dst
    const float* Wmu = (const float*)d_in[2];
    const float* bmu = (const float*)d_in[3];
    const float* Wls = (const float*)d_in[4];
    const float* bls = (const float*)d_in[5];
    float* out = (float*)d_out;

    char* ws = (char*)d_ws;
    size_t off = 0;
    auto alloc = [&](size_t bytes) {
        void* p = ws + off;
        off += (bytes + 255) & ~(size_t)255;
        return p;
    };
    unsigned short* hs = (unsigned short*)alloc((size_t)NN * OC * sizeof(unsigned short));  // 25.6 MB
    uint4* Wc = (uint4*)alloc((size_t)16384 * 16);                                          // 256 KB
    int* deg = (int*)alloc((size_t)NN * sizeof(int));
    int* row_start = (int*)alloc((size_t)(NN + 1) * sizeof(int));
    int* cursor = (int*)alloc((size_t)NN * sizeof(int));
    int* csr_src = (int*)alloc((size_t)NE * sizeof(int));
    float* dinv = (float*)alloc((size_t)NN * sizeof(float));
    int* partial = (int*)alloc((size_t)NB_SCAN * sizeof(int));

    hipMemsetAsync(deg, 0, (size_t)NN * sizeof(int), stream);

    prep0_kernel<<<NCB + 64, 256, 0, stream>>>(ei, deg, Wmu, Wls, Wc);
    scan_part_kernel<<<NB_SCAN, 256, 0, stream>>>(deg, partial);
    scan_apply_kernel<<<NB_SCAN, 256, 0, stream>>>(deg, partial, row_start, cursor, dinv);
    gemm_scatter_kernel<<<NGB + NCB, 256, 0, stream>>>(x, Wc, dinv, hs, ei, cursor, csr_src);
    aggregate_kernel<<<NN / 4, 256, 0, stream>>>(hs, row_start, csr_src, dinv, bmu, bls, out);
}

// Round 23
// 170.619 us; speedup vs baseline: 1.1517x; 1.0906x over previous
//
#include <hip/hip_runtime.h>

#define NN 50000
#define NE 800000
#define KC 512
#define OC 256  // 128 mu cols | 128 logstd cols
#define NB_SCAN 196   // ceil(NN/256)
#define NCB 3125      // ceil(NE/256) count blocks
#define NGB 1563      // ceil(NN/32) gemm blocks

typedef float f32x4 __attribute__((ext_vector_type(4)));
typedef short bf16x8 __attribute__((ext_vector_type(8)));

__device__ __forceinline__ unsigned f2bf(float f) {
    union { float f; unsigned u; } v; v.f = f;
    return (v.u + 0x7FFFu + ((v.u >> 16) & 1u)) >> 16;  // RNE
}
__device__ __forceinline__ float bf2f(unsigned short b) {
    union { unsigned u; float f; } v; v.u = ((unsigned)b) << 16;
    return v.f;
}

// ---------------- fused: degree count (blocks 0..NCB-1) + W convert (blocks NCB..) ----------------
__global__ __launch_bounds__(256) void prep0_kernel(const int* __restrict__ ei,
                                                    int* __restrict__ deg,
                                                    const float* __restrict__ Wmu,
                                                    const float* __restrict__ Wls,
                                                    uint4* __restrict__ Wc) {
    int bid = blockIdx.x;
    int tid = threadIdx.x;
    if (bid < NCB) {
        int e = bid * 256 + tid;
        if (e < NE) atomicAdd(&deg[ei[NE + e]], 1);
    } else {
        int idx = (bid - NCB) * 256 + tid;  // 16384 slots
        int kb = idx >> 10;
        int rem = idx & 1023;
        int wf = rem >> 6;
        int lane = rem & 63;
        int g4 = lane >> 4;
        int i16 = lane & 15;
        int col = (wf >> 2) * 64 + (wf & 3) * 16 + i16;
        int k0 = kb * 32 + g4 * 8;
        const float* Wsrc = (col < 128) ? (Wmu + col) : (Wls + (col - 128));
        unsigned o[4];
#pragma unroll
        for (int p = 0; p < 4; ++p) {
            float lo = Wsrc[(size_t)(k0 + 2 * p) * 128];
            float hi = Wsrc[(size_t)(k0 + 2 * p + 1) * 128];
            o[p] = f2bf(lo) | (f2bf(hi) << 16);
        }
        uint4 v;
        v.x = o[0]; v.y = o[1]; v.z = o[2]; v.w = o[3];
        Wc[idx] = v;
    }
}

// ---------------- scan A: per-block sums ----------------
__global__ __launch_bounds__(256) void scan_part_kernel(const int* __restrict__ deg,
                                                        int* __restrict__ partial) {
    int tid = threadIdx.x;
    int i = blockIdx.x * 256 + tid;
    int v = (i < NN) ? deg[i] : 0;
#pragma unroll
    for (int off = 32; off > 0; off >>= 1) v += __shfl_down(v, off, 64);
    __shared__ int wsum[4];
    if ((tid & 63) == 0) wsum[tid >> 6] = v;
    __syncthreads();
    if (tid == 0) partial[blockIdx.x] = wsum[0] + wsum[1] + wsum[2] + wsum[3];
}

// ---------------- scan B (fused): inline scan of 196 partials + per-block apply ----------------
__global__ __launch_bounds__(256) void scan_apply_kernel(const int* __restrict__ deg,
                                                         const int* __restrict__ partial,
                                                         int* __restrict__ row_start,
                                                         int* __restrict__ cursor,
                                                         float* __restrict__ dinv) {
    __shared__ int plds[256];
    __shared__ int wsum[4];
    int tid = threadIdx.x;
    int lane = tid & 63;
    int w = tid >> 6;

    int pv = (tid < NB_SCAN) ? partial[tid] : 0;
    plds[tid] = pv;
    __syncthreads();
    for (int off = 1; off < 256; off <<= 1) {
        int t = (tid >= off) ? plds[tid - off] : 0;
        __syncthreads();
        plds[tid] += t;
        __syncthreads();
    }
    int boff = (blockIdx.x == 0) ? 0 : plds[blockIdx.x - 1];

    int i = blockIdx.x * 256 + tid;
    int d = (i < NN) ? deg[i] : 0;
    int v = d;
#pragma unroll
    for (int off = 1; off < 64; off <<= 1) {
        int t = __shfl_up(v, off, 64);
        if (lane >= off) v += t;
    }
    if (lane == 63) wsum[w] = v;
    __syncthreads();
    int wof = 0;
    for (int k = 0; k < w; ++k) wof += wsum[k];
    int excl = boff + wof + v - d;
    if (i < NN) {
        row_start[i] = excl;
        cursor[i] = excl;
        dinv[i] = rsqrtf((float)(d + 1));  // +1 self-loop
    }
    if (i == NN - 1) row_start[NN] = excl + d;
}

// ---------------- MFMA GEMM with scatter folded into each block's tail ----------------
// GEMM (R12-proven): BM=32, 4 waves; A via global_load_lds DMA into f32 LDS, source
// pre-swizzled (c'=c^(r&15), m'=m^((r>>2&1)*4)); cvt_pk at frag read; B 3-buf reg prefetch.
// After the epilogue each block scatters its 512-edge slice (2 edges/thread) — no
// dedicated scatter blocks wasting LDS/VGPR reservations; work hides under other
// blocks' latency-bound gemm.
__global__ __launch_bounds__(256, 4) void gemm_scatter_kernel(const float* __restrict__ x,
                                                              const uint4* __restrict__ Wc,
                                                              const float* __restrict__ dinv,
                                                              unsigned short* __restrict__ hs,
                                                              const int* __restrict__ ei,
                                                              int* __restrict__ cursor,
                                                              int* __restrict__ csr_src) {
    __shared__ __align__(16) float Af[2][32 * 128];  // 2 x 16 KB

    int bid = blockIdx.x;
    int tid = threadIdx.x;
    int lane = tid & 63;
    int w = tid >> 6;
    int r0 = bid * 32;
    int i16 = lane & 15;
    int g4 = lane >> 4;

    const float* srcp[4];
#pragma unroll
    for (int j = 0; j < 4; ++j) {
        int r = w * 8 + j * 2 + (lane >> 5);
        int gr = r0 + r;
        if (gr > NN - 1) gr = NN - 1;
        int cp = (lane & 31) >> 1;
        int mp = (lane & 1) * 4;
        int c = cp ^ (r & 15);
        int m = mp ^ (((r >> 2) & 1) * 4);
        srcp[j] = x + (size_t)gr * KC + c * 8 + m;
    }
    auto dmaA = [&](int buf, int S) {
#pragma unroll
        for (int j = 0; j < 4; ++j) {
            __builtin_amdgcn_global_load_lds(
                (const __attribute__((address_space(1))) void*)(srcp[j] + S * 128),
                (__attribute__((address_space(3))) void*)&Af[buf][(w * 4 + j) * 256], 16, 0, 0);
        }
    };

    auto readA = [&](int buf, int ks, int fr) -> bf16x8 {
        int r = fr * 16 + i16;
        int c = ks * 4 + g4;
        int cc = c ^ (r & 15);
        int mo = ((r >> 2) & 1) * 4;
        const float* p = &Af[buf][r * 128 + cc * 8];
        f32x4 lo = *(const f32x4*)(p + mo);
        f32x4 hi = *(const f32x4*)(p + (mo ^ 4));
        unsigned o0, o1, o2, o3;
        asm("v_cvt_pk_bf16_f32 %0, %1, %2" : "=v"(o0) : "v"(lo.x), "v"(lo.y));
        asm("v_cvt_pk_bf16_f32 %0, %1, %2" : "=v"(o1) : "v"(lo.z), "v"(lo.w));
        asm("v_cvt_pk_bf16_f32 %0, %1, %2" : "=v"(o2) : "v"(hi.x), "v"(hi.y));
        asm("v_cvt_pk_bf16_f32 %0, %1, %2" : "=v"(o3) : "v"(hi.z), "v"(hi.w));
        union { unsigned u[4]; bf16x8 v; } res;
        res.u[0] = o0; res.u[1] = o1; res.u[2] = o2; res.u[3] = o3;
        return res.v;
    };

    const uint4* wbase = Wc + (size_t)(w * 4) * 64 + lane;
    uint4 bb[3][4];
    auto loadB = [&](int dbuf, int kb) {
#pragma unroll
        for (int fc = 0; fc < 4; ++fc) bb[dbuf][fc] = wbase[kb * 1024 + fc * 64];
    };

    f32x4 acc[2][4];
    f32x4 zz = {0.f, 0.f, 0.f, 0.f};
#pragma unroll
    for (int a = 0; a < 2; ++a)
#pragma unroll
        for (int b = 0; b < 4; ++b) acc[a][b] = zz;

    dmaA(0, 0);
    loadB(0, 0);
    loadB(1, 1);
    __syncthreads();  // drains DMA S0

#pragma unroll
    for (int S = 0; S < 4; ++S) {
        if (S < 3) dmaA((S + 1) & 1, S + 1);
#pragma unroll
        for (int ks = 0; ks < 4; ++ks) {
            const int kb = S * 4 + ks;
            if (kb + 2 < 16) loadB((kb + 2) % 3, kb + 2);
            bf16x8 af0 = readA(S & 1, ks, 0);
            bf16x8 af1 = readA(S & 1, ks, 1);
            const int cur = kb % 3;
#pragma unroll
            for (int fc = 0; fc < 4; ++fc) {
                bf16x8 bfrag = *(const bf16x8*)&bb[cur][fc];
                acc[0][fc] = __builtin_amdgcn_mfma_f32_16x16x32_bf16(af0, bfrag, acc[0][fc], 0, 0, 0);
                acc[1][fc] = __builtin_amdgcn_mfma_f32_16x16x32_bf16(af1, bfrag, acc[1][fc], 0, 0, 0);
            }
        }
        if (S < 3) __syncthreads();
    }

#pragma unroll
    for (int fr = 0; fr < 2; ++fr) {
#pragma unroll
        for (int r = 0; r < 4; ++r) {
            int gr = r0 + fr * 16 + g4 * 4 + r;
            if (gr < NN) {
                float dv = dinv[gr];
#pragma unroll
                for (int fc = 0; fc < 4; ++fc) {
                    int col = w * 64 + fc * 16 + i16;
                    hs[(size_t)gr * OC + col] = (unsigned short)f2bf(acc[fr][fc][r] * dv);
                }
            }
        }
    }

    // ---- scatter tail: this block's 512-edge slice (1563*512 >= NE) ----
    int e0 = bid * 512;
#pragma unroll
    for (int q = 0; q < 2; ++q) {
        int e = e0 + q * 256 + tid;
        if (e < NE) {
            int d = ei[NE + e];
            int pos = atomicAdd(&cursor[d], 1);
            csr_src[pos] = ei[e];
        }
    }
}

// ---------------- aggregation: out = dinv[n]*(sum_e hs[src] + hs[n]) + b ----------------
__global__ __launch_bounds__(256) void aggregate_kernel(const unsigned short* __restrict__ hs,
                                                        const int* __restrict__ row_start,
                                                        const int* __restrict__ csr_src,
                                                        const float* __restrict__ dinv,
                                                        const float* __restrict__ bmu,
                                                        const float* __restrict__ bls,
                                                        float* __restrict__ out) {
    int tid = threadIdx.x;
    int lane = tid & 63;
    int node = blockIdx.x * 4 + (tid >> 6);

    const unsigned short* hrow = hs + lane * 4;  // lane covers cols 4l..4l+3
    float acc0, acc1, acc2, acc3;
    {
        ushort4 v = *(const ushort4*)&hrow[(size_t)node * OC];
        acc0 = bf2f(v.x);
        acc1 = bf2f(v.y);
        acc2 = bf2f(v.z);
        acc3 = bf2f(v.w);
    }
    int rs = row_start[node], re = row_start[node + 1];
    int e = rs;
    for (; e + 8 <= re; e += 8) {
        int s[8];
#pragma unroll
        for (int q = 0; q < 8; ++q) s[q] = csr_src[e + q];
        ushort4 v[8];
#pragma unroll
        for (int q = 0; q < 8; ++q) v[q] = *(const ushort4*)&hrow[(size_t)s[q] * OC];
#pragma unroll
        for (int q = 0; q < 8; ++q) {
            acc0 += bf2f(v[q].x);
            acc1 += bf2f(v[q].y);
            acc2 += bf2f(v[q].z);
            acc3 += bf2f(v[q].w);
        }
    }
    if (e + 4 <= re) {
        int s[4];
#pragma unroll
        for (int q = 0; q < 4; ++q) s[q] = csr_src[e + q];
        ushort4 v[4];
#pragma unroll
        for (int q = 0; q < 4; ++q) v[q] = *(const ushort4*)&hrow[(size_t)s[q] * OC];
#pragma unroll
        for (int q = 0; q < 4; ++q) {
            acc0 += bf2f(v[q].x);
            acc1 += bf2f(v[q].y);
            acc2 += bf2f(v[q].z);
            acc3 += bf2f(v[q].w);
        }
        e += 4;
    }
    for (; e < re; ++e) {
        int s0 = csr_src[e];
        ushort4 v0 = *(const ushort4*)&hrow[(size_t)s0 * OC];
        acc0 += bf2f(v0.x);
        acc1 += bf2f(v0.y);
        acc2 += bf2f(v0.z);
        acc3 += bf2f(v0.w);
    }
    float dn = dinv[node];
    if (lane < 32) {
        f32x4 b = *(const f32x4*)&bmu[lane * 4];
        f32x4 r;
        r.x = acc0 * dn + b.x;
        r.y = acc1 * dn + b.y;
        r.z = acc2 * dn + b.z;
        r.w = acc3 * dn + b.w;
        __builtin_nontemporal_store(r, (f32x4*)(out + (size_t)node * 128 + lane * 4));
    } else {
        f32x4 b = *(const f32x4*)&bls[(lane - 32) * 4];
        f32x4 r;
        r.x = acc0 * dn + b.x;
        r.y = acc1 * dn + b.y;
        r.z = acc2 * dn + b.z;
        r.w = acc3 * dn + b.w;
        __builtin_nontemporal_store(
            r, (f32x4*)(out + (size_t)NN * 128 + (size_t)node * 128 + (lane - 32) * 4));
    }
}

extern "C" void kernel_launch(void* const* d_in, const int* in_sizes, int n_in,
                              void* d_out, int out_size, void* d_ws, size_t ws_size,
                              hipStream_t stream) {
    const float* x = (const float*)d_in[0];
    const int* ei = (const int*)d_in[1];  // [2][NE]: src then dst
    const float* Wmu = (const float*)d_in[2];
    const float* bmu = (const float*)d_in[3];
    const float* Wls = (const float*)d_in[4];
    const float* bls = (const float*)d_in[5];
    float* out = (float*)d_out;

    char* ws = (char*)d_ws;
    size_t off = 0;
    auto alloc = [&](size_t bytes) {
        void* p = ws + off;
        off += (bytes + 255) & ~(size_t)255;
        return p;
    };
    unsigned short* hs = (unsigned short*)alloc((size_t)NN * OC * sizeof(unsigned short));  // 25.6 MB
    uint4* Wc = (uint4*)alloc((size_t)16384 * 16);                                          // 256 KB
    int* deg = (int*)alloc((size_t)NN * sizeof(int));
    int* row_start = (int*)alloc((size_t)(NN + 1) * sizeof(int));
    int* cursor = (int*)alloc((size_t)NN * sizeof(int));
    int* csr_src = (int*)alloc((size_t)NE * sizeof(int));
    float* dinv = (float*)alloc((size_t)NN * sizeof(float));
    int* partial = (int*)alloc((size_t)NB_SCAN * sizeof(int));

    hipMemsetAsync(deg, 0, (size_t)NN * sizeof(int), stream);

    prep0_kernel<<<NCB + 64, 256, 0, stream>>>(ei, deg, Wmu, Wls, Wc);
    scan_part_kernel<<<NB_SCAN, 256, 0, stream>>>(deg, partial);
    scan_apply_kernel<<<NB_SCAN, 256, 0, stream>>>(deg, partial, row_start, cursor, dinv);
    gemm_scatter_kernel<<<NGB, 256, 0, stream>>>(x, Wc, dinv, hs, ei, cursor, csr_src);
    aggregate_kernel<<<NN / 4, 256, 0, stream>>>(hs, row_start, csr_src, dinv, bmu, bls, out);
}